// Round 2
// baseline (117.867 us; speedup 1.0000x reference)
//
#include <hip/hip_runtime.h>

// TensorProduct: out[b, seg[n], c] += CG[n] * x1[b, M1[n], c] * x2[b, M2[n], c]
// B=128, NUM_M=25, C=128, nnz ~ 6.5k, fp32. Rows sorted by (seg, M1, M2).
//
// Block = 1 wave (64 thr) = (m_out, batch-pair); lanes = 2 batches x 32 float4.
// x2 tiles for both batches staged in LDS (25.6 KB) -> per-entry gather is a
// ds_read_b128 instead of an L2 round-trip (L2 traffic 850 MB -> ~180 MB).
// M1-run hoisting (rows sorted by M1 within a segment): per run load x1 once,
// accumulate t = sum(w * x2[m2]) in registers, then acc += a * t. Halves FMAs
// and cuts x1 reads ~4x. New x1 load has the whole next run to cover latency.

#define NUM_M 25
#define C4    32               // float4 chunks per (b, m) row (C = 128)
#define TILE4 (NUM_M * C4)     // 800 float4 per batch tile

__device__ __forceinline__ int wave_lower_bound(const int* __restrict__ seg,
                                                int nnz, int key) {
    const int lane = threadIdx.x & 63;
    int lo = 0, hi = nnz;
    while (hi > lo) {
        const int len = hi - lo;
        const int S = (len + 63) >> 6;          // ceil(len/64)
        const int idx = lo + lane * S;
        bool pred = false;
        if (idx < hi) pred = (seg[idx] < key);
        const unsigned long long bal = __ballot(pred);
        const int c = __popcll(bal);
        if (c == 0) { hi = lo; break; }
        int nhi = lo + c * S;
        if (nhi > hi) nhi = hi;
        lo = lo + (c - 1) * S + 1;
        hi = nhi;
    }
    return lo;
}

__global__ __launch_bounds__(64) void tp_kernel(
    const float* __restrict__ x1, const float* __restrict__ x2,
    const float* __restrict__ cg, const int* __restrict__ M1,
    const int* __restrict__ M2, const int* __restrict__ seg,
    int nnz, float* __restrict__ out) {

    __shared__ float4 x2l[2 * TILE4];     // 25.6 KB -> 6 blocks/CU

    const int m    = blockIdx.x;          // output M index, fast-varying for balance
    const int bp   = blockIdx.y;          // batch pair
    const int lane = threadIdx.x;
    const int half = lane >> 5;           // which batch of the pair
    const int c4   = lane & 31;

    // Cooperative segment bounds (~1k cyc, overlapped across resident waves)
    const int lo = wave_lower_bound(seg, nnz, m);
    const int hi = wave_lower_bound(seg, nnz, m + 1);

    // Stage x2 for both batches (contiguous 25.6 KB) into LDS
    const float4* __restrict__ g2 = (const float4*)x2 + bp * (2 * TILE4);
    for (int i = lane; i < 2 * TILE4; i += 64)
        x2l[i] = g2[i];
    __syncthreads();

    const float4* __restrict__ x1t = (const float4*)x1 + (bp * 2 + half) * TILE4 + c4;
    const float4* __restrict__ l2t = x2l + half * TILE4 + c4;

    float4 acc = make_float4(0.f, 0.f, 0.f, 0.f);

    if (lo < hi) {
        int curM1 = M1[lo];                    // wave-uniform -> scalar loads
        float4 a  = x1t[curM1 * C4];           // L2-resident, once per run
        float4 t  = make_float4(0.f, 0.f, 0.f, 0.f);

        for (int n = lo; n < hi; ++n) {
            const float w  = cg[n];
            const int   m2 = M2[n];
            const float4 v = l2t[m2 * C4];     // ds_read_b128, 2-way bank alias (free)
            t.x = fmaf(w, v.x, t.x);
            t.y = fmaf(w, v.y, t.y);
            t.z = fmaf(w, v.z, t.z);
            t.w = fmaf(w, v.w, t.w);

            int nm1 = -1;
            if (n + 1 < hi) nm1 = M1[n + 1];   // uniform scalar branch
            if (nm1 != curM1) {                // run boundary
                acc.x = fmaf(a.x, t.x, acc.x);
                acc.y = fmaf(a.y, t.y, acc.y);
                acc.z = fmaf(a.z, t.z, acc.z);
                acc.w = fmaf(a.w, t.w, acc.w);
                t = make_float4(0.f, 0.f, 0.f, 0.f);
                if (nm1 >= 0) {
                    curM1 = nm1;
                    a = x1t[curM1 * C4];       // latency covered by next run
                }
            }
        }
    }

    ((float4*)out)[(bp * 2 + half) * TILE4 + m * C4 + c4] = acc;
}

extern "C" void kernel_launch(void* const* d_in, const int* in_sizes, int n_in,
                              void* d_out, int out_size, void* d_ws, size_t ws_size,
                              hipStream_t stream) {
    const float* x1  = (const float*)d_in[0];
    const float* x2  = (const float*)d_in[1];
    const float* cg  = (const float*)d_in[2];
    const int*   M1  = (const int*)d_in[3];
    const int*   M2  = (const int*)d_in[4];
    const int*   seg = (const int*)d_in[5];
    const int    nnz = in_sizes[2];
    float* out = (float*)d_out;

    dim3 grid(NUM_M, 64);   // 1600 one-wave blocks, m fast-varying
    tp_kernel<<<grid, 64, 0, stream>>>(x1, x2, cg, M1, M2, seg, nnz, out);
}

// Round 3
// 104.789 us; speedup vs baseline: 1.1248x; 1.1248x over previous
//
#include <hip/hip_runtime.h>

// TensorProduct as a dense bilinear form.
// Each COO row's (seg, M1, M2) triple is unique (l,m both encoded in the M
// index), so: out[b,mo,c] = sum_{m1,m2} W[mo][m1][m2] * x1[b,m1,c] * x2[b,m2,c]
// with dense W = scatter(CG_vals) of shape 25x25x25 (62.5 KB, ~42% dense —
// only ~2.4x the sparse FLOPs, but zero index/branch overhead).
//
// Kernel A: build W in d_ws (25 blocks, each zeroes + scatters its own mo-slice).
// Kernel B: one thread per output element (b,mo,c); W reads are wave-uniform
// (scalar s_load -> SGPR operand on v_fmac), x1/x2 columns in registers.
// 650 unrolled FMAs/thread, 6400 waves -> VALU floor ~3.5 us.

#define NUM_M 25
#define C_DIM 128
#define W_SZ  (NUM_M * NUM_M * NUM_M)   // 15625 floats

__global__ __launch_bounds__(256) void build_w(
    const float* __restrict__ cg, const int* __restrict__ M1,
    const int* __restrict__ M2, const int* __restrict__ seg,
    int nnz, float* __restrict__ W) {
    const int mo  = blockIdx.x;            // 0..24
    const int tid = threadIdx.x;
    float* Wmo = W + mo * (NUM_M * NUM_M);
    for (int i = tid; i < NUM_M * NUM_M; i += 256) Wmo[i] = 0.f;
    __syncthreads();
    for (int n = tid; n < nnz; n += 256) {
        if (seg[n] == mo)
            atomicAdd(&Wmo[M1[n] * NUM_M + M2[n]], cg[n]);
    }
}

__global__ __launch_bounds__(128) void tp_dense(
    const float* __restrict__ x1, const float* __restrict__ x2,
    const float* __restrict__ W, float* __restrict__ out) {
    const int c  = threadIdx.x;            // 0..127
    const int mo = blockIdx.x;             // 0..24
    const int b  = blockIdx.y;             // 0..127

    const float* __restrict__ Wm  = W  + mo * (NUM_M * NUM_M);   // wave-uniform
    const float* __restrict__ x1b = x1 + b * (NUM_M * C_DIM) + c;
    const float* __restrict__ x2b = x2 + b * (NUM_M * C_DIM) + c;

    float x2v[NUM_M], x1v[NUM_M];
#pragma unroll
    for (int m = 0; m < NUM_M; ++m) x2v[m] = x2b[m * C_DIM];   // coalesced
#pragma unroll
    for (int m = 0; m < NUM_M; ++m) x1v[m] = x1b[m * C_DIM];

    float acc0 = 0.f, acc1 = 0.f, acc2 = 0.f, acc3 = 0.f;
#pragma unroll
    for (int m1 = 0; m1 < NUM_M; ++m1) {
        const float* __restrict__ wr = Wm + m1 * NUM_M;          // uniform + const offsets
        float t0 = wr[24] * x2v[24];
        float t1 = 0.f, t2 = 0.f, t3 = 0.f;
#pragma unroll
        for (int m2 = 0; m2 < 24; m2 += 4) {
            t0 = fmaf(wr[m2 + 0], x2v[m2 + 0], t0);
            t1 = fmaf(wr[m2 + 1], x2v[m2 + 1], t1);
            t2 = fmaf(wr[m2 + 2], x2v[m2 + 2], t2);
            t3 = fmaf(wr[m2 + 3], x2v[m2 + 3], t3);
        }
        const float t = (t0 + t1) + (t2 + t3);
        switch (m1 & 3) {                   // 4 independent acc chains
            case 0: acc0 = fmaf(x1v[m1], t, acc0); break;
            case 1: acc1 = fmaf(x1v[m1], t, acc1); break;
            case 2: acc2 = fmaf(x1v[m1], t, acc2); break;
            default: acc3 = fmaf(x1v[m1], t, acc3); break;
        }
    }

    out[(b * NUM_M + mo) * C_DIM + c] = (acc0 + acc1) + (acc2 + acc3);
}

extern "C" void kernel_launch(void* const* d_in, const int* in_sizes, int n_in,
                              void* d_out, int out_size, void* d_ws, size_t ws_size,
                              hipStream_t stream) {
    const float* x1  = (const float*)d_in[0];
    const float* x2  = (const float*)d_in[1];
    const float* cg  = (const float*)d_in[2];
    const int*   M1  = (const int*)d_in[3];
    const int*   M2  = (const int*)d_in[4];
    const int*   seg = (const int*)d_in[5];
    const int    nnz = in_sizes[2];
    float* W   = (float*)d_ws;             // 62.5 KB dense CG tensor
    float* out = (float*)d_out;

    build_w<<<NUM_M, 256, 0, stream>>>(cg, M1, M2, seg, nnz, W);
    dim3 grid(NUM_M, 128);                 // (mo, b); block = c
    tp_dense<<<grid, 128, 0, stream>>>(x1, x2, W, out);
}

// Round 4
// 93.441 us; speedup vs baseline: 1.2614x; 1.1214x over previous
//
#include <hip/hip_runtime.h>

// TensorProduct as a dense bilinear form:
//   out[b,mo,c] = sum_{m1,m2} W[mo][m1][m2] * x1[b,m1,c] * x2[b,m2,c]
// W = dense scatter of CG_vals (25^3 = 62.5 KB in d_ws). (seg,M1,M2) triples
// are UNIQUE (l,m fully encoded in M index; generator emits each tuple once),
// so the scatter needs no atomics — plain stores after a zero pass.
//
// build_w: ONE 1024-thread block: zero 15625 floats, sync, scatter nnz entries.
// tp_dense: thread = (mo, b, c-pair). float2 per thread: halves the W
// scalar-load count per FMA and doubles per-wave FMA work to hide s_load
// latency. W reads are wave-uniform -> SGPR operands on v_fmac (no per-lane
// data movement, which is why W-in-LDS-broadcast would be slower).
// VALU floor: 276M lane-ops -> ~3.5 us across 1024 SIMDs.

#define NUM_M 25
#define C_DIM 128
#define W_ELEMS (NUM_M * NUM_M * NUM_M)   // 15625

__global__ __launch_bounds__(1024) void build_w(
    const float* __restrict__ cg, const int* __restrict__ M1,
    const int* __restrict__ M2, const int* __restrict__ seg,
    int nnz, float* __restrict__ W) {
    const int tid = threadIdx.x;
    for (int i = tid; i < W_ELEMS; i += 1024) W[i] = 0.f;
    __syncthreads();
    for (int n = tid; n < nnz; n += 1024) {
        // unique (seg,M1,M2) per row -> plain store, no atomic
        W[seg[n] * (NUM_M * NUM_M) + M1[n] * NUM_M + M2[n]] = cg[n];
    }
}

__global__ __launch_bounds__(64) void tp_dense(
    const float* __restrict__ x1, const float* __restrict__ x2,
    const float* __restrict__ W, float* __restrict__ out) {
    const int lane = threadIdx.x;          // 0..63 -> c-pair
    const int mo   = blockIdx.x;           // 0..24
    const int b    = blockIdx.y;           // 0..127

    const float*  __restrict__ Wm  = W + mo * (NUM_M * NUM_M);  // wave-uniform
    const float2* __restrict__ x1b = (const float2*)x1 + b * (NUM_M * 64) + lane;
    const float2* __restrict__ x2b = (const float2*)x2 + b * (NUM_M * 64) + lane;

    // Prefetch both operand columns (50 independent dwordx2 loads, coalesced)
    float2 x1v[NUM_M], x2v[NUM_M];
#pragma unroll
    for (int m = 0; m < NUM_M; ++m) x2v[m] = x2b[m * 64];
#pragma unroll
    for (int m = 0; m < NUM_M; ++m) x1v[m] = x1b[m * 64];

    float2 acc0 = {0.f, 0.f}, acc1 = {0.f, 0.f};
    float2 acc2 = {0.f, 0.f}, acc3 = {0.f, 0.f};

#pragma unroll
    for (int m1 = 0; m1 < NUM_M; ++m1) {
        const float* __restrict__ wr = Wm + m1 * NUM_M;   // uniform, const offsets
        // 4 independent t-chains over m2 (24 = 4x6), last element folded in
        float2 t0, t1, t2, t3;
        t0.x = wr[24] * x2v[24].x; t0.y = wr[24] * x2v[24].y;
        t1 = {0.f, 0.f}; t2 = {0.f, 0.f}; t3 = {0.f, 0.f};
#pragma unroll
        for (int m2 = 0; m2 < 24; m2 += 4) {
            t0.x = fmaf(wr[m2 + 0], x2v[m2 + 0].x, t0.x);
            t0.y = fmaf(wr[m2 + 0], x2v[m2 + 0].y, t0.y);
            t1.x = fmaf(wr[m2 + 1], x2v[m2 + 1].x, t1.x);
            t1.y = fmaf(wr[m2 + 1], x2v[m2 + 1].y, t1.y);
            t2.x = fmaf(wr[m2 + 2], x2v[m2 + 2].x, t2.x);
            t2.y = fmaf(wr[m2 + 2], x2v[m2 + 2].y, t2.y);
            t3.x = fmaf(wr[m2 + 3], x2v[m2 + 3].x, t3.x);
            t3.y = fmaf(wr[m2 + 3], x2v[m2 + 3].y, t3.y);
        }
        float2 t;
        t.x = (t0.x + t1.x) + (t2.x + t3.x);
        t.y = (t0.y + t1.y) + (t2.y + t3.y);
        const float2 a = x1v[m1];
        switch (m1 & 3) {                  // 4 independent accumulator chains
            case 0:  acc0.x = fmaf(a.x, t.x, acc0.x); acc0.y = fmaf(a.y, t.y, acc0.y); break;
            case 1:  acc1.x = fmaf(a.x, t.x, acc1.x); acc1.y = fmaf(a.y, t.y, acc1.y); break;
            case 2:  acc2.x = fmaf(a.x, t.x, acc2.x); acc2.y = fmaf(a.y, t.y, acc2.y); break;
            default: acc3.x = fmaf(a.x, t.x, acc3.x); acc3.y = fmaf(a.y, t.y, acc3.y); break;
        }
    }

    float2 r;
    r.x = (acc0.x + acc1.x) + (acc2.x + acc3.x);
    r.y = (acc0.y + acc1.y) + (acc2.y + acc3.y);
    ((float2*)out)[(b * NUM_M + mo) * 64 + lane] = r;
}

extern "C" void kernel_launch(void* const* d_in, const int* in_sizes, int n_in,
                              void* d_out, int out_size, void* d_ws, size_t ws_size,
                              hipStream_t stream) {
    const float* x1  = (const float*)d_in[0];
    const float* x2  = (const float*)d_in[1];
    const float* cg  = (const float*)d_in[2];
    const int*   M1  = (const int*)d_in[3];
    const int*   M2  = (const int*)d_in[4];
    const int*   seg = (const int*)d_in[5];
    const int    nnz = in_sizes[2];
    float* W   = (float*)d_ws;             // 62.5 KB dense CG tensor
    float* out = (float*)d_out;

    build_w<<<1, 1024, 0, stream>>>(cg, M1, M2, seg, nnz, W);
    dim3 grid(NUM_M, 128);                 // (mo, b); 64 threads = 64 c-pairs
    tp_dense<<<grid, 64, 0, stream>>>(x1, x2, W, out);
}